// Round 5
// baseline (769.466 us; speedup 1.0000x reference)
//
#include <hip/hip_runtime.h>
#include <hip/hip_bf16.h>
#include <stdint.h>

// Problem constants: x[16,256,64,64] f32; fc1[65,256]; fc2[1024,65]; fc2_b[1024];
// weight[4,256,256,3,3]; out[16,256,64,64] f32.

typedef __bf16 bf16x8 __attribute__((ext_vector_type(8)));
typedef float  f32x4  __attribute__((ext_vector_type(4)));

__device__ __forceinline__ unsigned short f2bf(float f) {
  union { float f; unsigned u; } v; v.f = f;
  return (unsigned short)((v.u + 0x7FFFu + ((v.u >> 16) & 1u)) >> 16);
}

__device__ __forceinline__ void gload16(const void* g, void* l) {
  __builtin_amdgcn_global_load_lds(
      (const __attribute__((address_space(1))) void*)g,
      (__attribute__((address_space(3))) void*)l, 16, 0, 0);
}

#define WAIT_VM(N) do { __builtin_amdgcn_sched_barrier(0); \
  asm volatile("s_waitcnt vmcnt(" #N ")" ::: "memory"); \
  __builtin_amdgcn_sched_barrier(0); } while (0)
#define BARRIER_PIN() do { __builtin_amdgcn_s_barrier(); \
  __builtin_amdgcn_sched_barrier(0); } while (0)
#define LGKM0_PIN() do { asm volatile("s_waitcnt lgkmcnt(0)" ::: "memory"); \
  __builtin_amdgcn_sched_barrier(0); } while (0)

// ---------------- Kernel A: pooling + NCHW f32 -> NHWC bf16 (r3 version) ----
// grid: 16 b * 4 cchunk * 64 y = 4096 blocks, 256 threads
__global__ __launch_bounds__(256) void k_prep(
    const float* __restrict__ x, unsigned short* __restrict__ xn,
    float* __restrict__ pooled_sum) {
  const int bx = blockIdx.x;
  const int y  = bx & 63;
  const int cc = (bx >> 6) & 3;
  const int b  = bx >> 8;
  const int t  = threadIdx.x;
  const int cl = t >> 2;
  const int q  = t & 3;
  const int xs = q * 16;

  const float4* s4 = (const float4*)(x + (((size_t)(b * 256 + cc * 64 + cl) * 64 + y) * 64 + xs));
  float v[16];
#pragma unroll
  for (int i = 0; i < 4; ++i) {
    float4 f = s4[i];
    v[i * 4 + 0] = f.x; v[i * 4 + 1] = f.y; v[i * 4 + 2] = f.z; v[i * 4 + 3] = f.w;
  }
  float s = 0.f;
#pragma unroll
  for (int i = 0; i < 16; ++i) s += v[i];
  s += __shfl_xor(s, 1);
  s += __shfl_xor(s, 2);
  if (q == 0) atomicAdd(&pooled_sum[b * 256 + cc * 64 + cl], s);

  __shared__ unsigned short tile[64][72];
#pragma unroll
  for (int j = 0; j < 16; ++j) tile[xs + j][cl] = f2bf(v[j]);
  __syncthreads();
  const int xp = t >> 2;
  const uint4* ls = (const uint4*)&tile[xp][q * 16];
  uint4 a0 = ls[0], a1 = ls[1];
  uint4* gd = (uint4*)(xn + ((size_t)((b * 64 + y) * 64 + xp) * 256 + cc * 64 + q * 16));
  gd[0] = a0; gd[1] = a1;
}

// ---------------- Kernel B1: fc1 -> relu -> fc2 -> softmax/T -> prob --------
__global__ __launch_bounds__(256) void k_fc(
    const float* __restrict__ pooled_sum,
    const float* __restrict__ fc1, const float* __restrict__ fc2,
    const float* __restrict__ fc2b, float* __restrict__ prob) {
  const int b = blockIdx.x, t = threadIdx.x;
  __shared__ float p[256];
  __shared__ float h[72];
  __shared__ float yv[1024];
  p[t] = pooled_sum[b * 256 + t] * (1.0f / 4096.0f);
  __syncthreads();
  if (t < 65) {
    float s = 0.f;
    for (int c = 0; c < 256; ++c) s += p[c] * fc1[t * 256 + c];
    h[t] = fmaxf(s, 0.f);
  }
  __syncthreads();
  for (int m = t; m < 1024; m += 256) {
    float s = fc2b[m];
    for (int j = 0; j < 65; ++j) s += h[j] * fc2[m * 65 + j];
    yv[m] = s;
  }
  __syncthreads();
  const float invT = 1.0f / 30.0f;
  float e0 = yv[t] * invT, e1 = yv[256 + t] * invT, e2 = yv[512 + t] * invT, e3 = yv[768 + t] * invT;
  float mx = fmaxf(fmaxf(e0, e1), fmaxf(e2, e3));
  float x0 = expf(e0 - mx), x1 = expf(e1 - mx), x2 = expf(e2 - mx), x3 = expf(e3 - mx);
  float r = 1.0f / (x0 + x1 + x2 + x3);
  prob[(b * 4 + 0) * 256 + t] = x0 * r;
  prob[(b * 4 + 1) * 256 + t] = x1 * r;
  prob[(b * 4 + 2) * 256 + t] = x2 * r;
  prob[(b * 4 + 3) * 256 + t] = x3 * r;
}

// ---------------- Kernel B2: aggT[b][tap][o][c] bf16 = sum_k prob*weight ----
__global__ __launch_bounds__(256) void k_agg(
    const float* __restrict__ weight, const float* __restrict__ prob,
    unsigned short* __restrict__ aggT) {
  const int o = blockIdx.x, t = threadIdx.x;
  __shared__ float w[4][2304];
#pragma unroll
  for (int k = 0; k < 4; ++k) {
    const float4* src = (const float4*)(weight + (size_t)(k * 256 + o) * 2304);
    float4* dst = (float4*)w[k];
    for (int j = t; j < 576; j += 256) dst[j] = src[j];
  }
  __syncthreads();
  const int c = t;
  float wv[4][9];
#pragma unroll
  for (int k = 0; k < 4; ++k)
#pragma unroll
    for (int tap = 0; tap < 9; ++tap) wv[k][tap] = w[k][c * 9 + tap];
  for (int b = 0; b < 16; ++b) {
    float p0 = prob[(b * 4 + 0) * 256 + o];
    float p1 = prob[(b * 4 + 1) * 256 + o];
    float p2 = prob[(b * 4 + 2) * 256 + o];
    float p3 = prob[(b * 4 + 3) * 256 + o];
#pragma unroll
    for (int tap = 0; tap < 9; ++tap) {
      float vv = p0 * wv[0][tap] + p1 * wv[1][tap] + p2 * wv[2][tap] + p3 * wv[3][tap];
      aggT[((size_t)(b * 9 + tap) * 256 + o) * 256 + c] = f2bf(vv);
    }
  }
}

// ---------------- Kernel C: per-sample implicit-GEMM conv, v5 ---------------
// Phase-decoupled pipeline: 36 phases (g = cc*9+tap), fully unrolled.
// Per phase: issue W(g+2) gloads -> counted vmcnt -> s_barrier -> lgkmcnt(0)
// [retires PREVIOUS phase's ds_reads, free] -> issue ds_reads for g+1 ->
// MFMA(g) on registers read one phase ago. MFMA cluster has zero same-phase
// dependencies; ds_read + W-prefetch latency each get a full phase to land.
// X single buffer (re-staged per cc, loads issued at tap-8, drained at tap-0);
// W ring-3. LDS 80KB -> 2 blocks/CU.
// grid: 16 b * 32 ytile * 2 otile = 1024 blocks, 256 threads
__global__ __launch_bounds__(256, 2) void k_conv(
    const unsigned short* __restrict__ xn,
    const unsigned short* __restrict__ aggT,
    const unsigned short* __restrict__ zpage,
    float* __restrict__ out) {
  const int bx0 = blockIdx.x;
  const int bx  = (bx0 & 7) * 128 + (bx0 >> 3);   // XCD swizzle: 2 samples/XCD
  const int ot = bx & 1;
  const int yt = (bx >> 1) & 31;
  const int b  = bx >> 6;
  const int y0 = yt * 2;
  const int o0 = ot * 128;
  const int t    = threadIdx.x;
  const int lane = t & 63;
  const int l15  = lane & 15;
  const int lg   = lane >> 4;
  const int wid  = t >> 6;
  const int wm   = wid >> 1;
  const int wn   = wid & 1;

  __shared__ unsigned short xbuf[256 * 64];      // 32 KiB
  __shared__ unsigned short wbuf[3][128 * 64];   // 3 x 16 KiB ring

  const f32x4 vzero = {0.f, 0.f, 0.f, 0.f};
  const bf16x8 bzero = {};
  f32x4 acc[4][4];
#pragma unroll
  for (int i = 0; i < 4; ++i)
#pragma unroll
    for (int j = 0; j < 4; ++j) acc[i][j] = vzero;

  const unsigned short* xb = xn + (size_t)b * (64 * 64 * 256);
  const unsigned short* ab = aggT + (size_t)b * (9 * 256 * 256) + (size_t)o0 * 256;

  // staging: 4 gload16 per thread for W(g), 8 for X(cc)
  auto stageW = [&](int g) {
    const int tap = g % 9, c0 = (g / 9) * 64;
    unsigned short* dst = wbuf[g % 3];
    const unsigned short* wsrc = ab + (size_t)tap * (256 * 256) + c0;
#pragma unroll
    for (int i = 0; i < 4; ++i) {
      int u = t + i * 256;
      int o = u >> 3, s = u & 7;
      gload16(wsrc + (size_t)o * 256 + ((s ^ (o & 7)) * 8), &dst[u * 8]);
    }
  };
  auto stageX = [&](int cc) {
    const int c0s = cc * 64;
#pragma unroll
    for (int i = 0; i < 8; ++i) {
      int u = t + i * 256;
      int pos = u >> 3, s = u & 7;
      int rr = pos >> 6, xc = pos & 63;
      int yy = y0 - 1 + rr;
      int sp = (s ^ (pos & 7)) * 8;
      const unsigned short* src = (yy >= 0 && yy < 64)
          ? xb + ((size_t)yy * 64 + xc) * 256 + (c0s + sp)
          : zpage + ((u & 127) * 8);
      gload16(src, &xbuf[u * 8]);
    }
  };
  auto readA = [&](bf16x8* av, int g) {   // av[ku*4+mf]
    const int tap = g % 9;
    const int kh = tap / 3, d = tap % 3 - 1;
    const int prow = (wm + kh) * 64;
#pragma unroll
    for (int ku = 0; ku < 2; ++ku)
#pragma unroll
      for (int mf = 0; mf < 4; ++mf) {
        int xsrc = mf * 16 + l15 + d;
        bool valid = (xsrc >= 0) && (xsrc < 64);
        int xcl = min(max(xsrc, 0), 63);
        int pos = prow + xcl;
        int su = (ku * 4 + lg) ^ (pos & 7);
        bf16x8 v = *(const bf16x8*)&xbuf[pos * 64 + su * 8];
        av[ku * 4 + mf] = valid ? v : bzero;
      }
  };
  auto readB = [&](bf16x8* bv, int g) {   // bv[ku*4+nf]
    const unsigned short* wb = wbuf[g % 3];
#pragma unroll
    for (int ku = 0; ku < 2; ++ku)
#pragma unroll
      for (int nf = 0; nf < 4; ++nf) {
        int oo = wn * 64 + nf * 16 + l15;
        int su = (ku * 4 + lg) ^ (oo & 7);
        bv[ku * 4 + nf] = *(const bf16x8*)&wb[oo * 64 + su * 8];
      }
  };

  bf16x8 avr[2][8], bvr[2][8];

  // prologue: X(0)[8] + W(0)[4] + W(1)[4]; keep W(1) in flight
  stageX(0);
  stageW(0);
  stageW(1);
  WAIT_VM(4);
  BARRIER_PIN();
  readA(avr[0], 0);
  readB(bvr[0], 0);

#pragma unroll
  for (int g = 0; g < 36; ++g) {
    if (g < 34) stageW(g + 2);
    if ((g % 9) == 8 && g < 35) stageX(g / 9 + 1);

    if (g < 35) {
      // steady: outstanding = {W(g+1), W(g+2)} -> vm(4) drains W(g+1).
      // tap-8: + 8 X' loads just issued -> vm(12) keeps {W(g+2), X'}.
      // g==34: only W(35) outstanding -> vm(0).
      if ((g % 9) == 8) { WAIT_VM(12); }
      else if (g == 34) { WAIT_VM(0); }
      else              { WAIT_VM(4); }
      BARRIER_PIN();
    }
    LGKM0_PIN();   // retire previous phase's ds_reads (issued ~1 phase ago)

    if ((g % 9) == 0 && g > 0) {   // deferred av(g): xbuf republished this phase
      readA(avr[g & 1], g);
      LGKM0_PIN();
    }
    if (g < 35) {
      if (((g + 1) % 9) == 0) {    // next phase republishes xbuf: defer its av
        readB(bvr[(g + 1) & 1], g + 1);
      } else {
        readA(avr[(g + 1) & 1], g + 1);
        readB(bvr[(g + 1) & 1], g + 1);
      }
    }

    __builtin_amdgcn_s_setprio(1);
#pragma unroll
    for (int ku = 0; ku < 2; ++ku)
#pragma unroll
      for (int mf = 0; mf < 4; ++mf)
#pragma unroll
        for (int nf = 0; nf < 4; ++nf)
          acc[mf][nf] = __builtin_amdgcn_mfma_f32_16x16x32_bf16(
              avr[g & 1][ku * 4 + mf], bvr[g & 1][ku * 4 + nf], acc[mf][nf], 0, 0, 0);
    __builtin_amdgcn_s_setprio(0);
  }

  // epilogue: D row = pixel = (lane>>4)*4 + reg, col = ochan = lane&15
  const int yrow = y0 + wm;
#pragma unroll
  for (int nf = 0; nf < 4; ++nf) {
    int och = o0 + wn * 64 + nf * 16 + l15;
    float* op = out + ((size_t)(b * 256 + och) * 4096) + yrow * 64;
#pragma unroll
    for (int mf = 0; mf < 4; ++mf) {
      int xcb = mf * 16 + lg * 4;
      *(float4*)(op + xcb) = *(float4*)&acc[mf][nf];
    }
  }
}

extern "C" void kernel_launch(void* const* d_in, const int* in_sizes, int n_in,
                              void* d_out, int out_size, void* d_ws, size_t ws_size,
                              hipStream_t stream) {
  (void)in_sizes; (void)n_in; (void)out_size; (void)ws_size;
  const float* x      = (const float*)d_in[0];
  const float* fc1    = (const float*)d_in[1];
  const float* fc2    = (const float*)d_in[2];
  const float* fc2b   = (const float*)d_in[3];
  const float* weight = (const float*)d_in[4];
  float* out = (float*)d_out;

  // workspace layout (~52.7 MB):
  //   [0,4K)            zero page (row-halo source for global_load_lds)
  //   [4K,20K)          pooled_sum f32[16][256]
  //   [20K, 86016)      prob f32[16][4][256]
  //   [131072, +18.87MB)  aggT bf16[16][9][256][256]
  //   [19,005,440, +33.55MB) x_nhwc bf16[16][64][64][256]
  char* ws = (char*)d_ws;
  unsigned short* zpage  = (unsigned short*)ws;
  float*          pooled = (float*)(ws + 4096);
  float*          prob   = (float*)(ws + 20480);
  unsigned short* aggT   = (unsigned short*)(ws + 131072);
  unsigned short* xnhwc  = (unsigned short*)(ws + 131072 + 18874368);

  hipMemsetAsync(d_ws, 0, 20480, stream);  // zero page + pooled_sum, every launch
  k_prep<<<dim3(16 * 4 * 64), dim3(256), 0, stream>>>(x, xnhwc, pooled);
  k_fc  <<<dim3(16),          dim3(256), 0, stream>>>(pooled, fc1, fc2, fc2b, prob);
  k_agg <<<dim3(256),         dim3(256), 0, stream>>>(weight, prob, aggT);
  k_conv<<<dim3(1024),        dim3(256), 0, stream>>>(xnhwc, aggT, zpage, out);
}

// Round 6
// 213.443 us; speedup vs baseline: 3.6050x; 3.6050x over previous
//
#include <hip/hip_runtime.h>
#include <hip/hip_bf16.h>
#include <stdint.h>

// Problem constants: x[16,256,64,64] f32; fc1[65,256]; fc2[1024,65]; fc2_b[1024];
// weight[4,256,256,3,3]; out[16,256,64,64] f32.

typedef __bf16 bf16x8 __attribute__((ext_vector_type(8)));
typedef float  f32x4  __attribute__((ext_vector_type(4)));

__device__ __forceinline__ unsigned short f2bf(float f) {
  union { float f; unsigned u; } v; v.f = f;
  return (unsigned short)((v.u + 0x7FFFu + ((v.u >> 16) & 1u)) >> 16);
}

__device__ __forceinline__ void gload16(const void* g, void* l) {
  __builtin_amdgcn_global_load_lds(
      (const __attribute__((address_space(1))) void*)g,
      (__attribute__((address_space(3))) void*)l, 16, 0, 0);
}

#define WAIT_VM(N) do { __builtin_amdgcn_sched_barrier(0); \
  asm volatile("s_waitcnt vmcnt(" #N ")" ::: "memory"); \
  __builtin_amdgcn_sched_barrier(0); } while (0)
#define BARRIER_PIN() do { __builtin_amdgcn_s_barrier(); \
  __builtin_amdgcn_sched_barrier(0); } while (0)

// ---------------- Kernel A: pooling + NCHW f32 -> NHWC bf16 (r3 version) ----
// grid: 16 b * 4 cchunk * 64 y = 4096 blocks, 256 threads
__global__ __launch_bounds__(256) void k_prep(
    const float* __restrict__ x, unsigned short* __restrict__ xn,
    float* __restrict__ pooled_sum) {
  const int bx = blockIdx.x;
  const int y  = bx & 63;
  const int cc = (bx >> 6) & 3;
  const int b  = bx >> 8;
  const int t  = threadIdx.x;
  const int cl = t >> 2;
  const int q  = t & 3;
  const int xs = q * 16;

  const float4* s4 = (const float4*)(x + (((size_t)(b * 256 + cc * 64 + cl) * 64 + y) * 64 + xs));
  float v[16];
#pragma unroll
  for (int i = 0; i < 4; ++i) {
    float4 f = s4[i];
    v[i * 4 + 0] = f.x; v[i * 4 + 1] = f.y; v[i * 4 + 2] = f.z; v[i * 4 + 3] = f.w;
  }
  float s = 0.f;
#pragma unroll
  for (int i = 0; i < 16; ++i) s += v[i];
  s += __shfl_xor(s, 1);
  s += __shfl_xor(s, 2);
  if (q == 0) atomicAdd(&pooled_sum[b * 256 + cc * 64 + cl], s);

  __shared__ unsigned short tile[64][72];
#pragma unroll
  for (int j = 0; j < 16; ++j) tile[xs + j][cl] = f2bf(v[j]);
  __syncthreads();
  const int xp = t >> 2;
  const uint4* ls = (const uint4*)&tile[xp][q * 16];
  uint4 a0 = ls[0], a1 = ls[1];
  uint4* gd = (uint4*)(xn + ((size_t)((b * 64 + y) * 64 + xp) * 256 + cc * 64 + q * 16));
  gd[0] = a0; gd[1] = a1;
}

// ---------------- Kernel B1: fc1 -> relu -> fc2 -> softmax/T -> prob --------
__global__ __launch_bounds__(256) void k_fc(
    const float* __restrict__ pooled_sum,
    const float* __restrict__ fc1, const float* __restrict__ fc2,
    const float* __restrict__ fc2b, float* __restrict__ prob) {
  const int b = blockIdx.x, t = threadIdx.x;
  __shared__ float p[256];
  __shared__ float h[72];
  __shared__ float yv[1024];
  p[t] = pooled_sum[b * 256 + t] * (1.0f / 4096.0f);
  __syncthreads();
  if (t < 65) {
    float s = 0.f;
    for (int c = 0; c < 256; ++c) s += p[c] * fc1[t * 256 + c];
    h[t] = fmaxf(s, 0.f);
  }
  __syncthreads();
  for (int m = t; m < 1024; m += 256) {
    float s = fc2b[m];
    for (int j = 0; j < 65; ++j) s += h[j] * fc2[m * 65 + j];
    yv[m] = s;
  }
  __syncthreads();
  const float invT = 1.0f / 30.0f;
  float e0 = yv[t] * invT, e1 = yv[256 + t] * invT, e2 = yv[512 + t] * invT, e3 = yv[768 + t] * invT;
  float mx = fmaxf(fmaxf(e0, e1), fmaxf(e2, e3));
  float x0 = expf(e0 - mx), x1 = expf(e1 - mx), x2 = expf(e2 - mx), x3 = expf(e3 - mx);
  float r = 1.0f / (x0 + x1 + x2 + x3);
  prob[(b * 4 + 0) * 256 + t] = x0 * r;
  prob[(b * 4 + 1) * 256 + t] = x1 * r;
  prob[(b * 4 + 2) * 256 + t] = x2 * r;
  prob[(b * 4 + 3) * 256 + t] = x3 * r;
}

// ---------------- Kernel B2: aggT[b][tap][o][c] bf16 = sum_k prob*weight ----
__global__ __launch_bounds__(256) void k_agg(
    const float* __restrict__ weight, const float* __restrict__ prob,
    unsigned short* __restrict__ aggT) {
  const int o = blockIdx.x, t = threadIdx.x;
  __shared__ float w[4][2304];
#pragma unroll
  for (int k = 0; k < 4; ++k) {
    const float4* src = (const float4*)(weight + (size_t)(k * 256 + o) * 2304);
    float4* dst = (float4*)w[k];
    for (int j = t; j < 576; j += 256) dst[j] = src[j];
  }
  __syncthreads();
  const int c = t;
  float wv[4][9];
#pragma unroll
  for (int k = 0; k < 4; ++k)
#pragma unroll
    for (int tap = 0; tap < 9; ++tap) wv[k][tap] = w[k][c * 9 + tap];
  for (int b = 0; b < 16; ++b) {
    float p0 = prob[(b * 4 + 0) * 256 + o];
    float p1 = prob[(b * 4 + 1) * 256 + o];
    float p2 = prob[(b * 4 + 2) * 256 + o];
    float p3 = prob[(b * 4 + 3) * 256 + o];
#pragma unroll
    for (int tap = 0; tap < 9; ++tap) {
      float vv = p0 * wv[0][tap] + p1 * wv[1][tap] + p2 * wv[2][tap] + p3 * wv[3][tap];
      aggT[((size_t)(b * 9 + tap) * 256 + o) * 256 + c] = f2bf(vv);
    }
  }
}

// ---------------- Kernel C: per-sample implicit-GEMM conv, v6 ---------------
// v5 pipeline (phase-decoupled: stage W(g+2) -> counted vmcnt -> barrier ->
// ds_reads for g+1 -> MFMA(g) on regs read last phase), but SCRATCH-PROOF:
// runtime half-loop (2 trips) x 18 macro-expanded phases; fragment sets are
// token-pasted av0/bv0/av1/bv1 -> every register index is a compile-time
// literal (rule #20). Ring = tt%3 (18%3==0 keeps it window-invariant).
// X single 32KB buffer, W ring-3 48KB; LDS 80KB -> 2 blocks/CU.
// grid: 16 b * 32 ytile * 2 otile = 1024 blocks, 256 threads
__global__ __launch_bounds__(256, 2) void k_conv(
    const unsigned short* __restrict__ xn,
    const unsigned short* __restrict__ aggT,
    const unsigned short* __restrict__ zpage,
    float* __restrict__ out) {
  const int bx0 = blockIdx.x;
  const int bx  = (bx0 & 7) * 128 + (bx0 >> 3);   // XCD swizzle: 2 samples/XCD
  const int ot = bx & 1;
  const int yt = (bx >> 1) & 31;
  const int b  = bx >> 6;
  const int y0 = yt * 2;
  const int o0 = ot * 128;
  const int t    = threadIdx.x;
  const int lane = t & 63;
  const int l15  = lane & 15;
  const int lg   = lane >> 4;
  const int wid  = t >> 6;
  const int wm   = wid >> 1;
  const int wn   = wid & 1;

  __shared__ unsigned short xbuf[256 * 64];      // 32 KiB
  __shared__ unsigned short wbuf[3][128 * 64];   // 3 x 16 KiB ring

  const f32x4 vzero = {0.f, 0.f, 0.f, 0.f};
  const bf16x8 bzero = {};
  f32x4 acc[4][4];
#pragma unroll
  for (int i = 0; i < 4; ++i)
#pragma unroll
    for (int j = 0; j < 4; ++j) acc[i][j] = vzero;

  const unsigned short* xb = xn + (size_t)b * (64 * 64 * 256);
  const unsigned short* ab = aggT + (size_t)b * (9 * 256 * 256) + (size_t)o0 * 256;

  auto stage_w = [&](int tap, int c0, unsigned short* dst) {
    const unsigned short* wsrc = ab + (size_t)tap * (256 * 256) + c0;
#pragma unroll
    for (int i = 0; i < 4; ++i) {
      int u = t + i * 256;
      int o = u >> 3, s = u & 7;
      gload16(wsrc + (size_t)o * 256 + ((s ^ (o & 7)) * 8), &dst[u * 8]);
    }
  };
  auto stage_x = [&](int cc) {
    const int c0s = cc * 64;
#pragma unroll
    for (int i = 0; i < 8; ++i) {
      int u = t + i * 256;
      int pos = u >> 3, s = u & 7;
      int rr = pos >> 6, xc = pos & 63;
      int yy = y0 - 1 + rr;
      int sp = (s ^ (pos & 7)) * 8;
      const unsigned short* src = (yy >= 0 && yy < 64)
          ? xb + ((size_t)yy * 64 + xc) * 256 + (c0s + sp)
          : zpage + ((u & 127) * 8);
      gload16(src, &xbuf[u * 8]);
    }
  };
  auto read_a = [&](bf16x8* av, int tap) {   // av[ku*4+mf]
    const int kh = tap / 3, d = tap % 3 - 1;
    const int prow = (wm + kh) * 64;
#pragma unroll
    for (int ku = 0; ku < 2; ++ku)
#pragma unroll
      for (int mf = 0; mf < 4; ++mf) {
        int xsrc = mf * 16 + l15 + d;
        bool valid = (xsrc >= 0) && (xsrc < 64);
        int xcl = min(max(xsrc, 0), 63);
        int pos = prow + xcl;
        int su = (ku * 4 + lg) ^ (pos & 7);
        bf16x8 v = *(const bf16x8*)&xbuf[pos * 64 + su * 8];
        av[ku * 4 + mf] = valid ? v : bzero;
      }
  };
  auto read_b = [&](bf16x8* bv, const unsigned short* wb) {  // bv[ku*4+nf]
#pragma unroll
    for (int ku = 0; ku < 2; ++ku)
#pragma unroll
      for (int nf = 0; nf < 4; ++nf) {
        int oo = wn * 64 + nf * 16 + l15;
        int su = (ku * 4 + lg) ^ (oo & 7);
        bv[ku * 4 + nf] = *(const bf16x8*)&wb[oo * 64 + su * 8];
      }
  };
  auto mfma_all = [&](bf16x8* av, bf16x8* bv) {
    __builtin_amdgcn_s_setprio(1);
#pragma unroll
    for (int ku = 0; ku < 2; ++ku)
#pragma unroll
      for (int mf = 0; mf < 4; ++mf)
#pragma unroll
        for (int nf = 0; nf < 4; ++nf)
          acc[mf][nf] = __builtin_amdgcn_mfma_f32_16x16x32_bf16(
              av[ku * 4 + mf], bv[ku * 4 + nf], acc[mf][nf], 0, 0, 0);
    __builtin_amdgcn_s_setprio(0);
  };

  bf16x8 av0[8], bv0[8], av1[8], bv1[8];

  // prologue: X(0)[8] + W(g0=0)->ring0 [4] + W(g1=1)->ring1 [4]
  stage_x(0);
  stage_w(0, 0, wbuf[0]);
  stage_w(1, 0, wbuf[1]);
  WAIT_VM(4);          // X + W0 landed; W1 in flight
  BARRIER_PIN();
  read_b(bv0, wbuf[0]);  // B(0); A(0) deferred to phase 0 (uniform tap0 path)

  // ---- 18-phase window, run twice (ccb = 0, 2). g = ccb*9 + TT.
  // Per phase TT: stage W(g+2) [+X' at tap8] -> counted vmcnt -> barrier ->
  // [tap0: deferred read_a(cur)] -> reads for g+1 into NXT set -> MFMA(CUR).
  // Outstanding-trace verified: steady {W(g+1),W(g+2)}->vm(4); tap8 adds X'
  // ->vm(12); endgame (ccb==2) vm(0)/none.
#define PH(TT, CUR, NXT) do {                                                  \
    if ((TT) <= 15 || ccb < 2)                                                 \
      stage_w(((TT) + 2) % 9, (ccb + ((TT) + 2) / 9) * 64, wbuf[((TT) + 2) % 3]); \
    if (((TT) % 9) == 8 && ((TT) == 8 || ccb < 2))                             \
      stage_x(ccb + (TT) / 9 + 1);                                             \
    if ((TT) == 8) { WAIT_VM(12); BARRIER_PIN(); }                             \
    else if ((TT) == 16) {                                                     \
      if (ccb < 2) { WAIT_VM(4); } else { WAIT_VM(0); }                        \
      BARRIER_PIN();                                                           \
    }                                                                          \
    else if ((TT) == 17) { if (ccb < 2) { WAIT_VM(12); BARRIER_PIN(); } }      \
    else { WAIT_VM(4); BARRIER_PIN(); }                                        \
    if (((TT) % 9) == 0) read_a(av##CUR, 0);                                   \
    if (((TT) % 9) == 8) {                                                     \
      if ((TT) == 8 || ccb < 2) read_b(bv##NXT, wbuf[((TT) + 1) % 3]);         \
    } else {                                                                   \
      read_a(av##NXT, ((TT) + 1) % 9);                                         \
      read_b(bv##NXT, wbuf[((TT) + 1) % 3]);                                   \
    }                                                                          \
    mfma_all(av##CUR, bv##CUR);                                                \
  } while (0)

  for (int half = 0; half < 2; ++half) {
    const int ccb = half * 2;
    PH(0, 0, 1);  PH(1, 1, 0);  PH(2, 0, 1);  PH(3, 1, 0);
    PH(4, 0, 1);  PH(5, 1, 0);  PH(6, 0, 1);  PH(7, 1, 0);
    PH(8, 0, 1);  PH(9, 1, 0);  PH(10, 0, 1); PH(11, 1, 0);
    PH(12, 0, 1); PH(13, 1, 0); PH(14, 0, 1); PH(15, 1, 0);
    PH(16, 0, 1); PH(17, 1, 0);
  }
#undef PH

  // epilogue: D row = pixel = (lane>>4)*4 + reg, col = ochan = lane&15
  const int yrow = y0 + wm;
#pragma unroll
  for (int nf = 0; nf < 4; ++nf) {
    int och = o0 + wn * 64 + nf * 16 + l15;
    float* op = out + ((size_t)(b * 256 + och) * 4096) + yrow * 64;
#pragma unroll
    for (int mf = 0; mf < 4; ++mf) {
      int xcb = mf * 16 + lg * 4;
      *(float4*)(op + xcb) = *(float4*)&acc[mf][nf];
    }
  }
}

extern "C" void kernel_launch(void* const* d_in, const int* in_sizes, int n_in,
                              void* d_out, int out_size, void* d_ws, size_t ws_size,
                              hipStream_t stream) {
  (void)in_sizes; (void)n_in; (void)out_size; (void)ws_size;
  const float* x      = (const float*)d_in[0];
  const float* fc1    = (const float*)d_in[1];
  const float* fc2    = (const float*)d_in[2];
  const float* fc2b   = (const float*)d_in[3];
  const float* weight = (const float*)d_in[4];
  float* out = (float*)d_out;

  // workspace layout (~52.7 MB):
  //   [0,4K)            zero page (row-halo source for global_load_lds)
  //   [4K,20K)          pooled_sum f32[16][256]
  //   [20K, 86016)      prob f32[16][4][256]
  //   [131072, +18.87MB)  aggT bf16[16][9][256][256]
  //   [19,005,440, +33.55MB) x_nhwc bf16[16][64][64][256]
  char* ws = (char*)d_ws;
  unsigned short* zpage  = (unsigned short*)ws;
  float*          pooled = (float*)(ws + 4096);
  float*          prob   = (float*)(ws + 20480);
  unsigned short* aggT   = (unsigned short*)(ws + 131072);
  unsigned short* xnhwc  = (unsigned short*)(ws + 131072 + 18874368);

  hipMemsetAsync(d_ws, 0, 20480, stream);  // zero page + pooled_sum, every launch
  k_prep<<<dim3(16 * 4 * 64), dim3(256), 0, stream>>>(x, xnhwc, pooled);
  k_fc  <<<dim3(16),          dim3(256), 0, stream>>>(pooled, fc1, fc2, fc2b, prob);
  k_agg <<<dim3(256),         dim3(256), 0, stream>>>(weight, prob, aggT);
  k_conv<<<dim3(1024),        dim3(256), 0, stream>>>(xnhwc, aggT, zpage, out);
}

// Round 8
// 134.803 us; speedup vs baseline: 5.7081x; 1.5834x over previous
//
#include <hip/hip_runtime.h>
#include <hip/hip_bf16.h>
#include <stdint.h>

// Problem constants: x[16,256,64,64] f32; fc1[65,256]; fc2[1024,65]; fc2_b[1024];
// weight[4,256,256,3,3]; out[16,256,64,64] f32.

typedef __bf16 bf16x8 __attribute__((ext_vector_type(8)));
typedef float  f32x4  __attribute__((ext_vector_type(4)));

__device__ __forceinline__ unsigned short f2bf(float f) {
  union { float f; unsigned u; } v; v.f = f;
  return (unsigned short)((v.u + 0x7FFFu + ((v.u >> 16) & 1u)) >> 16);
}

__device__ __forceinline__ void gload16(const void* g, void* l) {
  __builtin_amdgcn_global_load_lds(
      (const __attribute__((address_space(1))) void*)g,
      (__attribute__((address_space(3))) void*)l, 16, 0, 0);
}

#define WAIT_VM(N) do { __builtin_amdgcn_sched_barrier(0); \
  asm volatile("s_waitcnt vmcnt(" #N ")" ::: "memory"); \
  __builtin_amdgcn_sched_barrier(0); } while (0)
#define BARRIER_PIN() do { __builtin_amdgcn_s_barrier(); \
  __builtin_amdgcn_sched_barrier(0); } while (0)
#define LGKM0_PIN() do { asm volatile("s_waitcnt lgkmcnt(0)" ::: "memory"); \
  __builtin_amdgcn_sched_barrier(0); } while (0)

// ---------------- Kernel A: pooling + NCHW f32 -> NHWC bf16 (r3 version) ----
// grid: 16 b * 4 cchunk * 64 y = 4096 blocks, 256 threads
__global__ __launch_bounds__(256) void k_prep(
    const float* __restrict__ x, unsigned short* __restrict__ xn,
    float* __restrict__ pooled_sum) {
  const int bx = blockIdx.x;
  const int y  = bx & 63;
  const int cc = (bx >> 6) & 3;
  const int b  = bx >> 8;
  const int t  = threadIdx.x;
  const int cl = t >> 2;
  const int q  = t & 3;
  const int xs = q * 16;

  const float4* s4 = (const float4*)(x + (((size_t)(b * 256 + cc * 64 + cl) * 64 + y) * 64 + xs));
  float v[16];
#pragma unroll
  for (int i = 0; i < 4; ++i) {
    float4 f = s4[i];
    v[i * 4 + 0] = f.x; v[i * 4 + 1] = f.y; v[i * 4 + 2] = f.z; v[i * 4 + 3] = f.w;
  }
  float s = 0.f;
#pragma unroll
  for (int i = 0; i < 16; ++i) s += v[i];
  s += __shfl_xor(s, 1);
  s += __shfl_xor(s, 2);
  if (q == 0) atomicAdd(&pooled_sum[b * 256 + cc * 64 + cl], s);

  __shared__ unsigned short tile[64][72];
#pragma unroll
  for (int j = 0; j < 16; ++j) tile[xs + j][cl] = f2bf(v[j]);
  __syncthreads();
  const int xp = t >> 2;
  const uint4* ls = (const uint4*)&tile[xp][q * 16];
  uint4 a0 = ls[0], a1 = ls[1];
  uint4* gd = (uint4*)(xn + ((size_t)((b * 64 + y) * 64 + xp) * 256 + cc * 64 + q * 16));
  gd[0] = a0; gd[1] = a1;
}

// ---------------- Kernel B1: fc1 -> relu -> fc2 -> softmax/T -> prob --------
__global__ __launch_bounds__(256) void k_fc(
    const float* __restrict__ pooled_sum,
    const float* __restrict__ fc1, const float* __restrict__ fc2,
    const float* __restrict__ fc2b, float* __restrict__ prob) {
  const int b = blockIdx.x, t = threadIdx.x;
  __shared__ float p[256];
  __shared__ float h[72];
  __shared__ float yv[1024];
  p[t] = pooled_sum[b * 256 + t] * (1.0f / 4096.0f);
  __syncthreads();
  if (t < 65) {
    float s = 0.f;
    for (int c = 0; c < 256; ++c) s += p[c] * fc1[t * 256 + c];
    h[t] = fmaxf(s, 0.f);
  }
  __syncthreads();
  for (int m = t; m < 1024; m += 256) {
    float s = fc2b[m];
    for (int j = 0; j < 65; ++j) s += h[j] * fc2[m * 65 + j];
    yv[m] = s;
  }
  __syncthreads();
  const float invT = 1.0f / 30.0f;
  float e0 = yv[t] * invT, e1 = yv[256 + t] * invT, e2 = yv[512 + t] * invT, e3 = yv[768 + t] * invT;
  float mx = fmaxf(fmaxf(e0, e1), fmaxf(e2, e3));
  float x0 = expf(e0 - mx), x1 = expf(e1 - mx), x2 = expf(e2 - mx), x3 = expf(e3 - mx);
  float r = 1.0f / (x0 + x1 + x2 + x3);
  prob[(b * 4 + 0) * 256 + t] = x0 * r;
  prob[(b * 4 + 1) * 256 + t] = x1 * r;
  prob[(b * 4 + 2) * 256 + t] = x2 * r;
  prob[(b * 4 + 3) * 256 + t] = x3 * r;
}

// ---------------- Kernel B2: aggT[b][tap][o][c] bf16 = sum_k prob*weight ----
__global__ __launch_bounds__(256) void k_agg(
    const float* __restrict__ weight, const float* __restrict__ prob,
    unsigned short* __restrict__ aggT) {
  const int o = blockIdx.x, t = threadIdx.x;
  __shared__ float w[4][2304];
#pragma unroll
  for (int k = 0; k < 4; ++k) {
    const float4* src = (const float4*)(weight + (size_t)(k * 256 + o) * 2304);
    float4* dst = (float4*)w[k];
    for (int j = t; j < 576; j += 256) dst[j] = src[j];
  }
  __syncthreads();
  const int c = t;
  float wv[4][9];
#pragma unroll
  for (int k = 0; k < 4; ++k)
#pragma unroll
    for (int tap = 0; tap < 9; ++tap) wv[k][tap] = w[k][c * 9 + tap];
  for (int b = 0; b < 16; ++b) {
    float p0 = prob[(b * 4 + 0) * 256 + o];
    float p1 = prob[(b * 4 + 1) * 256 + o];
    float p2 = prob[(b * 4 + 2) * 256 + o];
    float p3 = prob[(b * 4 + 3) * 256 + o];
#pragma unroll
    for (int tap = 0; tap < 9; ++tap) {
      float vv = p0 * wv[0][tap] + p1 * wv[1][tap] + p2 * wv[2][tap] + p3 * wv[3][tap];
      aggT[((size_t)(b * 9 + tap) * 256 + o) * 256 + c] = f2bf(vv);
    }
  }
}

// ---------------- Kernel C: per-sample implicit-GEMM conv, v8 ---------------
// Fully read-ahead phases, race-free:
//  - ALL fragments for phase t+1 are read at the END of phase t: A-reads
//    issued BEFORE the counted vmcnt (xbuf stable mid-cc; they overlap the
//    MFMA cluster in the same sched region), B-reads right after the barrier
//    that publishes W(t+1). MFMA phases touch registers only.
//  - X republish hole closed: end of tap7 has lgkmcnt(0)+s_barrier, retiring
//    every wave's tap8 xbuf reads BEFORE any wave issues stage_x in tap8.
//    (v7's failure: stage_x data landed mid-phase over still-pending reads.)
//  - counted vmcnt: steady vm(4); tap8 drains {W(g+1),X'} keeping W(g+2);
//    cc3 tail vm(0). W ring-3 (slot = tap%3), X single 32KB. LDS 80KB.
// grid: 16 b * 32 ytile * 2 otile = 1024 blocks, 256 threads
__global__ __launch_bounds__(256, 2) void k_conv(
    const unsigned short* __restrict__ xn,
    const unsigned short* __restrict__ aggT,
    const unsigned short* __restrict__ zpage,
    float* __restrict__ out) {
  const int bx0 = blockIdx.x;
  const int bx  = (bx0 & 7) * 128 + (bx0 >> 3);   // XCD swizzle: 2 samples/XCD
  const int ot = bx & 1;
  const int yt = (bx >> 1) & 31;
  const int b  = bx >> 6;
  const int y0 = yt * 2;
  const int o0 = ot * 128;
  const int t    = threadIdx.x;
  const int lane = t & 63;
  const int l15  = lane & 15;
  const int lg   = lane >> 4;
  const int wid  = t >> 6;
  const int wm   = wid >> 1;
  const int wn   = wid & 1;

  __shared__ unsigned short xbuf[256 * 64];      // 32 KiB
  __shared__ unsigned short wbuf[3][128 * 64];   // 3 x 16 KiB ring

  const f32x4 vzero = {0.f, 0.f, 0.f, 0.f};
  const bf16x8 bzero = {};
  f32x4 acc[4][4];
#pragma unroll
  for (int i = 0; i < 4; ++i)
#pragma unroll
    for (int j = 0; j < 4; ++j) acc[i][j] = vzero;

  const unsigned short* xb = xn + (size_t)b * (64 * 64 * 256);
  const unsigned short* ab = aggT + (size_t)b * (9 * 256 * 256) + (size_t)o0 * 256;

  // staging lambdas take only ints (no fragment pointers -> SROA-safe)
  auto stage_w = [&](int tap, int ccs) {
    unsigned short* dst = wbuf[tap % 3];
    const unsigned short* wsrc = ab + (size_t)tap * (256 * 256) + ccs * 64;
#pragma unroll
    for (int i = 0; i < 4; ++i) {
      int u = t + i * 256;
      int o = u >> 3, s = u & 7;
      gload16(wsrc + (size_t)o * 256 + ((s ^ (o & 7)) * 8), &dst[u * 8]);
    }
  };
  auto stage_x = [&](int ccs) {
    const int c0s = ccs * 64;
#pragma unroll
    for (int i = 0; i < 8; ++i) {
      int u = t + i * 256;
      int pos = u >> 3, s = u & 7;
      int rr = pos >> 6, xc = pos & 63;
      int yy = y0 - 1 + rr;
      int sp = (s ^ (pos & 7)) * 8;
      const unsigned short* src = (yy >= 0 && yy < 64)
          ? xb + ((size_t)yy * 64 + xc) * 256 + (c0s + sp)
          : zpage + ((u & 127) * 8);
      gload16(src, &xbuf[u * 8]);
    }
  };

// inline fragment-read macros (no pointer escape, all-literal indices)
#define READ_A1(I, KU, MF, TAP) do {                                    \
    const int kh_ = (TAP) / 3, d_ = (TAP) % 3 - 1;                      \
    int xsrc_ = (MF) * 16 + l15 + d_;                                   \
    bool valid_ = (xsrc_ >= 0) && (xsrc_ < 64);                         \
    int pos_ = (wm + kh_) * 64 + min(max(xsrc_, 0), 63);                \
    int su_ = ((KU) * 4 + lg) ^ (pos_ & 7);                             \
    bf16x8 v_ = *(const bf16x8*)&xbuf[pos_ * 64 + su_ * 8];             \
    av[I] = valid_ ? v_ : bzero;                                        \
  } while (0)
#define READ_A_ALL(TAP) do {                                            \
    READ_A1(0, 0, 0, TAP); READ_A1(1, 0, 1, TAP);                       \
    READ_A1(2, 0, 2, TAP); READ_A1(3, 0, 3, TAP);                       \
    READ_A1(4, 1, 0, TAP); READ_A1(5, 1, 1, TAP);                       \
    READ_A1(6, 1, 2, TAP); READ_A1(7, 1, 3, TAP);                       \
  } while (0)
#define READ_B1(I, KU, NF, SLOT) do {                                   \
    int oo_ = wn * 64 + (NF) * 16 + l15;                                \
    int su_ = ((KU) * 4 + lg) ^ (oo_ & 7);                              \
    bv[I] = *(const bf16x8*)&wbuf[SLOT][oo_ * 64 + su_ * 8];            \
  } while (0)
#define READ_B_ALL(SLOT) do {                                           \
    READ_B1(0, 0, 0, SLOT); READ_B1(1, 0, 1, SLOT);                     \
    READ_B1(2, 0, 2, SLOT); READ_B1(3, 0, 3, SLOT);                     \
    READ_B1(4, 1, 0, SLOT); READ_B1(5, 1, 1, SLOT);                     \
    READ_B1(6, 1, 2, SLOT); READ_B1(7, 1, 3, SLOT);                     \
  } while (0)
#define MFMA4(AI, KU, MF) do {                                          \
    acc[MF][0] = __builtin_amdgcn_mfma_f32_16x16x32_bf16(av[AI], bv[(KU)*4+0], acc[MF][0], 0, 0, 0); \
    acc[MF][1] = __builtin_amdgcn_mfma_f32_16x16x32_bf16(av[AI], bv[(KU)*4+1], acc[MF][1], 0, 0, 0); \
    acc[MF][2] = __builtin_amdgcn_mfma_f32_16x16x32_bf16(av[AI], bv[(KU)*4+2], acc[MF][2], 0, 0, 0); \
    acc[MF][3] = __builtin_amdgcn_mfma_f32_16x16x32_bf16(av[AI], bv[(KU)*4+3], acc[MF][3], 0, 0, 0); \
  } while (0)
#define MFMA_ALL() do {                                                 \
    __builtin_amdgcn_s_setprio(1);                                      \
    MFMA4(0, 0, 0); MFMA4(1, 0, 1); MFMA4(2, 0, 2); MFMA4(3, 0, 3);     \
    MFMA4(4, 1, 0); MFMA4(5, 1, 1); MFMA4(6, 1, 2); MFMA4(7, 1, 3);     \
    __builtin_amdgcn_s_setprio(0);                                      \
  } while (0)

  bf16x8 av[8], bv[8];   // fragments for the CURRENT tap (read last phase)

  // prologue: X(0)[8] + W(0)->slot0 [4] + W(1)->slot1 [4]
  stage_x(0);
  stage_w(0, 0);
  stage_w(1, 0);
  WAIT_VM(4);            // X + W0 landed; W1 in flight
  BARRIER_PIN();
  READ_B_ALL(0);
  READ_A_ALL(0);

  for (int cc = 0; cc < 4; ++cc) {
#pragma unroll
    for (int tap = 0; tap < 9; ++tap) {
      // --- stage next tiles (tap8: xbuf is clean -- retired at tap7-end) ---
      if (tap == 8 && cc < 3) stage_x(cc + 1);
      if (cc < 3 || tap <= 6) stage_w((tap + 2) % 9, cc + (tap + 2) / 9);

      // --- MFMA(tap): registers only ---
      MFMA_ALL();

      // --- end-of-phase: sync + read fragments for tap+1 ---
      if (tap < 7) {
        READ_A_ALL(tap + 1);    // pre-vm: xbuf stable; overlaps MFMA drain
        WAIT_VM(4);             // drains W(g+1); keeps W(g+2)
        BARRIER_PIN();
        READ_B_ALL((tap + 1) % 3);
      } else if (tap == 7) {
        READ_A_ALL(8);          // current xbuf, pre-vm
        if (cc < 3) { WAIT_VM(4); } else { WAIT_VM(0); }
        BARRIER_PIN();
        READ_B_ALL(2);          // slot 8%3
        if (cc < 3) {           // retire ALL waves' xbuf reads before tap8's
          LGKM0_PIN();          // stage_x can overwrite xbuf
          BARRIER_PIN();
        }
      } else {                  // tap == 8
        if (cc < 3) {
          WAIT_VM(4);           // drains {W(g+1), X'}; keeps W(g+2)
          BARRIER_PIN();
          READ_B_ALL(0);        // slot 9%3 -> next cc tap0
          READ_A_ALL(0);        // new xbuf (landed)
        }                       // cc==3: fall through to epilogue
      }
    }
  }
#undef READ_A1
#undef READ_A_ALL
#undef READ_B1
#undef READ_B_ALL
#undef MFMA4
#undef MFMA_ALL

  // epilogue: D row = pixel = (lane>>4)*4 + reg, col = ochan = lane&15
  const int yrow = y0 + wm;
#pragma unroll
  for (int nf = 0; nf < 4; ++nf) {
    int och = o0 + wn * 64 + nf * 16 + l15;
    float* op = out + ((size_t)(b * 256 + och) * 4096) + yrow * 64;
#pragma unroll
    for (int mf = 0; mf < 4; ++mf) {
      int xcb = mf * 16 + lg * 4;
      *(float4*)(op + xcb) = *(float4*)&acc[mf][nf];
    }
  }
}

extern "C" void kernel_launch(void* const* d_in, const int* in_sizes, int n_in,
                              void* d_out, int out_size, void* d_ws, size_t ws_size,
                              hipStream_t stream) {
  (void)in_sizes; (void)n_in; (void)out_size; (void)ws_size;
  const float* x      = (const float*)d_in[0];
  const float* fc1    = (const float*)d_in[1];
  const float* fc2    = (const float*)d_in[2];
  const float* fc2b   = (const float*)d_in[3];
  const float* weight = (const float*)d_in[4];
  float* out = (float*)d_out;

  // workspace layout (~52.7 MB):
  //   [0,4K)            zero page (row-halo source for global_load_lds)
  //   [4K,20K)          pooled_sum f32[16][256]
  //   [20K, 86016)      prob f32[16][4][256]
  //   [131072, +18.87MB)  aggT bf16[16][9][256][256]
  //   [19,005,440, +33.55MB) x_nhwc bf16[16][64][64][256]
  char* ws = (char*)d_ws;
  unsigned short* zpage  = (unsigned short*)ws;
  float*          pooled = (float*)(ws + 4096);
  float*          prob   = (float*)(ws + 20480);
  unsigned short* aggT   = (unsigned short*)(ws + 131072);
  unsigned short* xnhwc  = (unsigned short*)(ws + 131072 + 18874368);

  hipMemsetAsync(d_ws, 0, 20480, stream);  // zero page + pooled_sum, every launch
  k_prep<<<dim3(16 * 4 * 64), dim3(256), 0, stream>>>(x, xnhwc, pooled);
  k_fc  <<<dim3(16),          dim3(256), 0, stream>>>(pooled, fc1, fc2, fc2b, prob);
  k_agg <<<dim3(256),         dim3(256), 0, stream>>>(weight, prob, aggT);
  k_conv<<<dim3(1024),        dim3(256), 0, stream>>>(xnhwc, aggT, zpage, out);
}